// Round 1
// baseline (99.666 us; speedup 1.0000x reference)
//
#include <hip/hip_runtime.h>

#define C_ROWS 32768
#define L_COLS 512
#define N_TOT  (C_ROWS * (size_t)L_COLS)
#define NB_A   2048   // blocks for rows kernel; 4 waves/block -> 8192 waves -> 4 rows/wave

// ws layout (bytes):
//   [0, 80)    : 10 doubles — masked-stats accumulators (zeroed by detect kernel)
//   [80, 84)   : int flag — mask storage: 0=bool byte, 1=int32, 2=float32
//   [128, ...) : NB_A * 2 doubles — rows-kernel per-block partials (misc, sse)

__device__ __forceinline__ float frelu(float x) { return x > 0.f ? x : 0.f; }

__device__ __forceinline__ float f4c(const float4& v, int k) {
    switch (k) { case 0: return v.x; case 1: return v.y; case 2: return v.z; default: return v.w; }
}

__device__ __forceinline__ bool mask_at(const void* p, int i, int flag) {
    if (flag == 1) return ((const int*)p)[i] != 0;
    if (flag == 2) return ((const float*)p)[i] != 0.f;
    return ((const unsigned char*)p)[i] != 0;
}

// ---------------------------------------------------------------- detect ----
__global__ void detect_kernel(const void* mask_nl, void* ws) {
    const int tid = threadIdx.x;                 // 64 threads
    const unsigned char* mb = (const unsigned char*)mask_nl;
    int mid_nz = 0, has3f = 0;
    for (int i = tid * 512; i < tid * 512 + 512; ++i) {
        unsigned char b = mb[i];
        if ((i & 3) && b) mid_nz = 1;
        if (b == 0x3f) has3f = 1;
    }
    unsigned long long bm = __ballot(mid_nz);
    unsigned long long bf = __ballot(has3f);
    if (tid < 10) ((double*)ws)[tid] = 0.0;
    if (tid == 0) {
        int flag = (bm == 0ull) ? 1 : (bf ? 2 : 0);
        *((int*)((char*)ws + 80)) = flag;
    }
}

// ----------------------------------------------------------------- stats ----
__global__ __launch_bounds__(256) void stats_kernel(const float* __restrict__ V,
                                                    const float* __restrict__ J,
                                                    const float* __restrict__ R,
                                                    const void* __restrict__ mask_nl,
                                                    void* ws) {
    const int flag = *((const int*)((const char*)ws + 80));
    double a[10];
#pragma unroll
    for (int k = 0; k < 10; ++k) a[k] = 0.0;
    for (int i = blockIdx.x * blockDim.x + threadIdx.x; i < C_ROWS; i += gridDim.x * blockDim.x) {
        float v = V[i], j = J[i], r = R[i];
        if (mask_at(mask_nl, i, flag)) {
            a[0] += 1.0;
            a[1] += (double)v; a[2] += (double)v * v;
            a[3] += (double)j; a[4] += (double)j * j; a[5] += (double)j * v;
            a[6] += (double)r; a[7] += (double)r * r; a[8] += (double)r * v;
        }
        a[9] += (double)frelu(-r);
    }
#pragma unroll
    for (int k = 0; k < 10; ++k)
        for (int off = 32; off; off >>= 1) a[k] += __shfl_xor(a[k], off);
    if ((threadIdx.x & 63) == 0) {
#pragma unroll
        for (int k = 0; k < 10; ++k) atomicAdd(&((double*)ws)[k], a[k]);
    }
}

// ------------------------------------------------------------------ rows ----
__global__ __launch_bounds__(256) void rows_kernel(const float* __restrict__ An,
                                                   const float* __restrict__ Ac,
                                                   const float* __restrict__ Aj,
                                                   const float* __restrict__ Ap,
                                                   const float* __restrict__ Ar,
                                                   const void* __restrict__ mFitAp,
                                                   const void* __restrict__ mFitAj,
                                                   void* ws) {
    const int lane = threadIdx.x & 63;
    const int wv   = threadIdx.x >> 6;           // wave within block (0..3)
    const int wid  = blockIdx.x * 4 + wv;
    const int nwaves = gridDim.x * 4;
    const int flag = *((const int*)((const char*)ws + 80));

    double miscAcc = 0.0, sseAcc = 0.0;

    for (int c = wid; c < C_ROWS; c += nwaves) {
        const size_t base = (size_t)c * L_COLS;
        float bestv = 3.4e38f; int besti = 1 << 30;
        float bAj = 0.f, bAp = 0.f;
        float lsAj = 0.f, lsAc = 0.f;
        float eAc = 0.f, eAj = 0.f, eAp = 0.f;
        double sse = 0.0, apneg = 0.0;

#pragma unroll
        for (int j = 0; j < 2; ++j) {
            const int col0 = j * 256 + lane * 4;
            const float4 ac = *(const float4*)(Ac + base + col0);
            const float4 aj = *(const float4*)(Aj + base + col0);
            const float4 ap = *(const float4*)(Ap + base + col0);
            const float4 an = *(const float4*)(An + base + col0);
            const float4 ar = *(const float4*)(Ar + base + col0);
#pragma unroll
            for (int k = 0; k < 4; ++k) {
                const int col = col0 + k;
                const float acv = f4c(ac, k), ajv = f4c(aj, k), apv = f4c(ap, k);
                const float d0 = f4c(an, k) - f4c(ar, k);
                sse   += (double)(d0 * d0);
                apneg += (double)frelu(-apv);
                if (col < L_COLS - 1) {
                    const float dd = acv - ajv;          // diff = Ac - Aj
                    lsAj += frelu(-dd);
                    lsAc += frelu(dd);
                    const float ad = fabsf(dd);
                    if (ad < bestv) { bestv = ad; besti = col; bAj = ajv; bAp = apv; }
                } else {                                  // col == 511 (lane 63)
                    eAc = acv; eAj = ajv; eAp = apv;
                }
            }
        }

        // wave reductions
#pragma unroll
        for (int off = 32; off; off >>= 1) {
            const float ov  = __shfl_xor(bestv, off);
            const int   oi  = __shfl_xor(besti, off);
            const float oaj = __shfl_xor(bAj, off);
            const float oap = __shfl_xor(bAp, off);
            if (ov < bestv || (ov == bestv && oi < besti)) {
                bestv = ov; besti = oi; bAj = oaj; bAp = oap;
            }
            lsAj  += __shfl_xor(lsAj, off);
            lsAc  += __shfl_xor(lsAc, off);
            sse   += __shfl_xor(sse, off);
            apneg += __shfl_xor(apneg, off);
        }
        eAc = __shfl(eAc, 63); eAj = __shfl(eAj, 63); eAp = __shfl(eAp, 63);

        if (lane == 0) {
            const float mAp = mask_at(mFitAp, c, flag) ? 1.f : 0.f;
            const float mAj = mask_at(mFitAj, c, flag) ? 1.f : 0.f;
            double t = 0.15 * (double)(mAp * frelu(eAp - eAj))
                     + (double)(mAj * frelu(eAj - eAc))
                     + 5.0 * (double)frelu(1.1f * bAj - bAp)
                     + (double)(mAj * (frelu(8.f - lsAj) + frelu(8.f - lsAc)))
                     + apneg;
            miscAcc += t;
            sseAcc  += sse;
        }
    }

    __shared__ double smisc[4], ssse[4];
    if (lane == 0) { smisc[wv] = miscAcc; ssse[wv] = sseAcc; }
    __syncthreads();
    if (threadIdx.x == 0) {
        double m = 0.0, s = 0.0;
#pragma unroll
        for (int i = 0; i < 4; ++i) { m += smisc[i]; s += ssse[i]; }
        double* part = (double*)((char*)ws + 128);
        part[blockIdx.x * 2]     = m;
        part[blockIdx.x * 2 + 1] = s;
    }
}

// ----------------------------------------------------------------- final ----
__device__ double corrterm(double n, double Sx, double Sxx, double Sy, double Syy,
                           double Sxy, double target) {
    const double mx = Sx / n, my = Sy / n;
    const double cov = Sxy - n * mx * my;
    const double vx  = Sxx - n * mx * mx;
    const double vy  = Syy - n * my * my;
    double cost = cov / (sqrt(vx) * sqrt(vy));
    if (isnan(cost)) cost = 0.0;
    const double cmin = cost < target ? cost : target;
    return target - cmin;
}

__global__ __launch_bounds__(1024) void final_kernel(const float* __restrict__ dHaV,
                                                     const float* __restrict__ dHaJ,
                                                     const float* __restrict__ dHaT,
                                                     const float* __restrict__ ToV,
                                                     const float* __restrict__ ToJ,
                                                     const float* __restrict__ ToT,
                                                     const float* __restrict__ gm,
                                                     void* ws, float* out) {
    __shared__ double sm[1024], ss[1024];
    double m = 0.0, s = 0.0;
    const double* part = (const double*)((const char*)ws + 128);
    for (int i = threadIdx.x; i < NB_A; i += 1024) { m += part[2 * i]; s += part[2 * i + 1]; }
    sm[threadIdx.x] = m; ss[threadIdx.x] = s;
    __syncthreads();
    for (int off = 512; off; off >>= 1) {
        if (threadIdx.x < (unsigned)off) {
            sm[threadIdx.x] += sm[threadIdx.x + off];
            ss[threadIdx.x] += ss[threadIdx.x + off];
        }
        __syncthreads();
    }
    if (threadIdx.x == 0) {
        double total = sm[0] + 10.0 * ss[0] / (double)N_TOT;
        const double* st = (const double*)ws;
        // x=Jmax25, y=Vcmax25, target 0.7
        total += corrterm(st[0], st[3], st[4], st[1], st[2], st[5], 0.7);
        // x=Rd25, y=Vcmax25, target 0.4
        total += corrterm(st[0], st[6], st[7], st[1], st[2], st[8], 0.4);
        total += st[9];                     // sum(relu(-Rd25))
        double p = 0.0;
        for (int i = 0; i < 8; ++i) {
            p += 10.0 * (double)frelu(-dHaV[i]) + (double)frelu(-dHaJ[i]) + (double)frelu(-dHaT[i]);
            p += (double)frelu(273.15f - ToV[i]) + (double)frelu(273.15f - ToJ[i])
               + (double)frelu(273.15f - ToT[i]);
            p += (double)frelu(-gm[i]);
        }
        total += p;
        out[0] = (float)total;
    }
}

extern "C" void kernel_launch(void* const* d_in, const int* in_sizes, int n_in,
                              void* d_out, int out_size, void* d_ws, size_t ws_size,
                              hipStream_t stream) {
    const float* An  = (const float*)d_in[0];
    const float* Ac  = (const float*)d_in[1];
    const float* Aj  = (const float*)d_in[2];
    const float* Ap  = (const float*)d_in[3];
    const float* Ar  = (const float*)d_in[4];
    const float* V   = (const float*)d_in[5];
    const float* J   = (const float*)d_in[6];
    const float* R   = (const float*)d_in[7];
    const float* dHaV = (const float*)d_in[8];
    const float* dHaJ = (const float*)d_in[9];
    const float* dHaT = (const float*)d_in[10];
    const float* ToV  = (const float*)d_in[11];
    const float* ToJ  = (const float*)d_in[12];
    const float* ToT  = (const float*)d_in[13];
    const float* gmv  = (const float*)d_in[14];
    const void* mNL = d_in[15];
    const void* mFp = d_in[16];
    const void* mFj = d_in[17];

    detect_kernel<<<1, 64, 0, stream>>>(mNL, d_ws);
    stats_kernel<<<32, 256, 0, stream>>>(V, J, R, mNL, d_ws);
    rows_kernel<<<NB_A, 256, 0, stream>>>(An, Ac, Aj, Ap, Ar, mFp, mFj, d_ws);
    final_kernel<<<1, 1024, 0, stream>>>(dHaV, dHaJ, dHaT, ToV, ToJ, ToT, gmv, d_ws,
                                         (float*)d_out);
}

// Round 2
// 87.856 us; speedup vs baseline: 1.1344x; 1.1344x over previous
//
#include <hip/hip_runtime.h>

#define C_ROWS 32768
#define L_COLS 512
#define N_TOT  (C_ROWS * (size_t)L_COLS)

#define NB_R   512                 // row-logic blocks: 64 rows each, 4 waves split cols
#define NB_S   1536                // streaming SSE blocks
#define NB_ST  32                  // stats blocks (folded in)
#define NB_TOT (NB_R + NB_S)       // partial slots (stats uses atomics, no slot)
#define GRID   (NB_R + NB_S + NB_ST)

#define CW      16                 // cols per chunk
#define NCH     (L_COLS / CW)      // 32 chunks; wave w handles ch = w, w+4, ...
#define CSTRIDE 68                 // padded col stride in LDS floats (bank-conflict-free)

// ws layout (bytes):
//   [0, 80)    : 10 doubles — masked-stats accumulators (zeroed by detect kernel)
//   [80, 84)   : int flag — mask storage: 0=bool byte, 1=int32, 2=float32
//   [128, ...) : NB_TOT * 2 doubles — per-block partials (misc, sse)

__device__ __forceinline__ float frelu(float x) { return x > 0.f ? x : 0.f; }

__device__ __forceinline__ bool mask_at(const void* p, int i, int flag) {
    if (flag == 1) return ((const int*)p)[i] != 0;
    if (flag == 2) return ((const float*)p)[i] != 0.f;
    return ((const unsigned char*)p)[i] != 0;
}

// ---------------------------------------------------------------- detect ----
__global__ void detect_kernel(const void* mask_nl, void* ws) {
    const int tid = threadIdx.x;                 // 64 threads
    const unsigned char* mb = (const unsigned char*)mask_nl;
    int mid_nz = 0, has3f = 0;
    for (int i = tid * 512; i < tid * 512 + 512; ++i) {
        unsigned char b = mb[i];
        if ((i & 3) && b) mid_nz = 1;
        if (b == 0x3f) has3f = 1;
    }
    unsigned long long bm = __ballot(mid_nz);
    unsigned long long bf = __ballot(has3f);
    if (tid < 10) ((double*)ws)[tid] = 0.0;
    if (tid == 0) {
        int flag = (bm == 0ull) ? 1 : (bf ? 2 : 0);
        *((int*)((char*)ws + 80)) = flag;
    }
}

// ----------------------------------------------------------------- fused ----
__global__ __launch_bounds__(256) void fused_kernel(const float* __restrict__ An,
                                                    const float* __restrict__ Ac,
                                                    const float* __restrict__ Aj,
                                                    const float* __restrict__ Ap,
                                                    const float* __restrict__ Ar,
                                                    const float* __restrict__ V,
                                                    const float* __restrict__ J,
                                                    const float* __restrict__ R,
                                                    const void* __restrict__ mNL,
                                                    const void* __restrict__ mFp,
                                                    const void* __restrict__ mFj,
                                                    void* ws) {
    double* part = (double*)((char*)ws + 128);

    if (blockIdx.x < NB_R) {
        // ---------------- Part B: row logic (Ac, Aj, Ap), 64 rows per block ----
        __shared__ float sbuf[4][3][CW * CSTRIDE];   // per-wave staging, 52.2 KB
        const int lane = threadIdx.x & 63;
        const int wv   = threadIdx.x >> 6;
        const int R0   = blockIdx.x * 64;
        const int flag = *((const int*)((const char*)ws + 80));

        const int rr = lane >> 2;       // row-within-16-group for staging
        const int g  = lane & 3;        // col group for staging

        float4 buf[3][4];
        float bestv = 3.4e38f; int besti = 0x7fffffff;
        float bAj = 0.f, bAp = 0.f, lsAj = 0.f, lsAc = 0.f, apneg = 0.f;
        float eAc = 0.f, eAj = 0.f, eAp = 0.f;

        const float* srcAc = Ac; const float* srcAj = Aj; const float* srcAp = Ap;

        auto LOAD = [&](int c) {
#pragma unroll
            for (int i = 0; i < 4; ++i) {
                const size_t rowoff = (size_t)(R0 + i * 16 + rr) * L_COLS + c * CW + g * 4;
                buf[0][i] = *(const float4*)(srcAc + rowoff);
                buf[1][i] = *(const float4*)(srcAj + rowoff);
                buf[2][i] = *(const float4*)(srcAp + rowoff);
            }
        };

        LOAD(wv);
        for (int ch = wv; ch < NCH; ch += 4) {
            // regs -> LDS (col-major, padded stride: conflict-free reads)
#pragma unroll
            for (int a = 0; a < 3; ++a) {
                float* dst = &sbuf[wv][a][0];
#pragma unroll
                for (int i = 0; i < 4; ++i) {
                    const int r = i * 16 + rr;
                    dst[(g * 4 + 0) * CSTRIDE + r] = buf[a][i].x;
                    dst[(g * 4 + 1) * CSTRIDE + r] = buf[a][i].y;
                    dst[(g * 4 + 2) * CSTRIDE + r] = buf[a][i].z;
                    dst[(g * 4 + 3) * CSTRIDE + r] = buf[a][i].w;
                }
            }
            if (ch + 4 < NCH) LOAD(ch + 4);     // prefetch next chunk (hides HBM latency)

            const int c0 = ch * CW;
#pragma unroll
            for (int cc = 0; cc < CW; ++cc) {   // lane == row here
                const float acv = sbuf[wv][0][cc * CSTRIDE + lane];
                const float ajv = sbuf[wv][1][cc * CSTRIDE + lane];
                const float apv = sbuf[wv][2][cc * CSTRIDE + lane];
                const int col = c0 + cc;
                apneg += frelu(-apv);
                if (col < L_COLS - 1) {
                    const float dd = acv - ajv;
                    lsAj += frelu(-dd);
                    lsAc += frelu(dd);
                    const float ad = fabsf(dd);
                    if (ad < bestv) { bestv = ad; besti = col; bAj = ajv; bAp = apv; }
                } else { eAc = acv; eAj = ajv; eAp = apv; }
            }
        }

        __syncthreads();                         // all waves done with sbuf
        float* mg = &sbuf[0][0][0];              // reuse as merge buffer [4][64][10]
        {
            float* m = mg + (wv * 64 + lane) * 10;
            m[0] = bestv; m[1] = __int_as_float(besti);
            m[2] = bAj;  m[3] = bAp; m[4] = lsAj; m[5] = lsAc; m[6] = apneg;
            m[7] = eAc;  m[8] = eAj; m[9] = eAp;
        }
        __syncthreads();

        if (wv == 0) {
            const float* b0 = mg + lane * 10;
            float bv = b0[0]; int bi = __float_as_int(b0[1]);
            float bj = b0[2], bp = b0[3];
            float lA = b0[4], lC = b0[5], ap = b0[6];
            float ec = 0.f, ej = 0.f, ep = 0.f;
#pragma unroll
            for (int w = 1; w < 4; ++w) {
                const float* q = mg + (w * 64 + lane) * 10;
                const float ov = q[0]; const int oi = __float_as_int(q[1]);
                if (ov < bv || (ov == bv && oi < bi)) { bv = ov; bi = oi; bj = q[2]; bp = q[3]; }
                lA += q[4]; lC += q[5]; ap += q[6];
                if (w == 3) { ec = q[7]; ej = q[8]; ep = q[9]; }
            }
            const int row = R0 + lane;
            const float mAp = mask_at(mFp, row, flag) ? 1.f : 0.f;
            const float mAj = mask_at(mFj, row, flag) ? 1.f : 0.f;
            double misc = 0.15 * (double)(mAp * frelu(ep - ej))
                        + (double)(mAj * frelu(ej - ec))
                        + 5.0 * (double)frelu(1.1f * bj - bp)
                        + (double)(mAj * (frelu(8.f - lA) + frelu(8.f - lC)))
                        + (double)ap;
#pragma unroll
            for (int off = 32; off; off >>= 1) misc += __shfl_xor(misc, off);
            if (lane == 0) { part[2 * blockIdx.x] = misc; part[2 * blockIdx.x + 1] = 0.0; }
        }
    } else if (blockIdx.x < NB_R + NB_S) {
        // ---------------- Part A: streaming SSE over An, Ar --------------------
        const size_t i0 = (size_t)(blockIdx.x - NB_R) * 256 + threadIdx.x;
        const size_t stride = (size_t)NB_S * 256;
        const size_t N4 = N_TOT / 4;
        const float4* a4 = (const float4*)An;
        const float4* r4 = (const float4*)Ar;
        double sse = 0.0;
        for (size_t i = i0; i < N4; i += stride) {
            const float4 a = a4[i], r = r4[i];
            const float dx = a.x - r.x, dy = a.y - r.y, dz = a.z - r.z, dw = a.w - r.w;
            sse += (double)(dx * dx + dy * dy + dz * dz + dw * dw);
        }
#pragma unroll
        for (int off = 32; off; off >>= 1) sse += __shfl_xor(sse, off);
        __shared__ double ssse[4];
        if ((threadIdx.x & 63) == 0) ssse[threadIdx.x >> 6] = sse;
        __syncthreads();
        if (threadIdx.x == 0) {
            const double s = ssse[0] + ssse[1] + ssse[2] + ssse[3];
            part[2 * blockIdx.x] = 0.0;
            part[2 * blockIdx.x + 1] = s;
        }
    } else {
        // ---------------- Part C: masked stats over C-length arrays ------------
        const int flag = *((const int*)((const char*)ws + 80));
        double a[10];
#pragma unroll
        for (int k = 0; k < 10; ++k) a[k] = 0.0;
        for (int i = (blockIdx.x - NB_R - NB_S) * 256 + threadIdx.x; i < C_ROWS;
             i += NB_ST * 256) {
            const float v = V[i], j = J[i], r = R[i];
            if (mask_at(mNL, i, flag)) {
                a[0] += 1.0;
                a[1] += (double)v; a[2] += (double)v * v;
                a[3] += (double)j; a[4] += (double)j * j; a[5] += (double)j * v;
                a[6] += (double)r; a[7] += (double)r * r; a[8] += (double)r * v;
            }
            a[9] += (double)frelu(-r);
        }
#pragma unroll
        for (int k = 0; k < 10; ++k)
            for (int off = 32; off; off >>= 1) a[k] += __shfl_xor(a[k], off);
        if ((threadIdx.x & 63) == 0) {
#pragma unroll
            for (int k = 0; k < 10; ++k) atomicAdd(&((double*)ws)[k], a[k]);
        }
    }
}

// ----------------------------------------------------------------- final ----
__device__ double corrterm(double n, double Sx, double Sxx, double Sy, double Syy,
                           double Sxy, double target) {
    const double mx = Sx / n, my = Sy / n;
    const double cov = Sxy - n * mx * my;
    const double vx  = Sxx - n * mx * mx;
    const double vy  = Syy - n * my * my;
    double cost = cov / (sqrt(vx) * sqrt(vy));
    if (isnan(cost)) cost = 0.0;
    const double cmin = cost < target ? cost : target;
    return target - cmin;
}

__global__ __launch_bounds__(1024) void final_kernel(const float* __restrict__ dHaV,
                                                     const float* __restrict__ dHaJ,
                                                     const float* __restrict__ dHaT,
                                                     const float* __restrict__ ToV,
                                                     const float* __restrict__ ToJ,
                                                     const float* __restrict__ ToT,
                                                     const float* __restrict__ gm,
                                                     void* ws, float* out) {
    __shared__ double sm[1024], ss[1024];
    double m = 0.0, s = 0.0;
    const double* part = (const double*)((const char*)ws + 128);
    for (int i = threadIdx.x; i < NB_TOT; i += 1024) { m += part[2 * i]; s += part[2 * i + 1]; }
    sm[threadIdx.x] = m; ss[threadIdx.x] = s;
    __syncthreads();
    for (int off = 512; off; off >>= 1) {
        if (threadIdx.x < (unsigned)off) {
            sm[threadIdx.x] += sm[threadIdx.x + off];
            ss[threadIdx.x] += ss[threadIdx.x + off];
        }
        __syncthreads();
    }
    if (threadIdx.x == 0) {
        double total = sm[0] + 10.0 * ss[0] / (double)N_TOT;
        const double* st = (const double*)ws;
        total += corrterm(st[0], st[3], st[4], st[1], st[2], st[5], 0.7);
        total += corrterm(st[0], st[6], st[7], st[1], st[2], st[8], 0.4);
        total += st[9];                     // sum(relu(-Rd25))
        double p = 0.0;
        for (int i = 0; i < 8; ++i) {
            p += 10.0 * (double)frelu(-dHaV[i]) + (double)frelu(-dHaJ[i]) + (double)frelu(-dHaT[i]);
            p += (double)frelu(273.15f - ToV[i]) + (double)frelu(273.15f - ToJ[i])
               + (double)frelu(273.15f - ToT[i]);
            p += (double)frelu(-gm[i]);
        }
        total += p;
        out[0] = (float)total;
    }
}

extern "C" void kernel_launch(void* const* d_in, const int* in_sizes, int n_in,
                              void* d_out, int out_size, void* d_ws, size_t ws_size,
                              hipStream_t stream) {
    const float* An  = (const float*)d_in[0];
    const float* Ac  = (const float*)d_in[1];
    const float* Aj  = (const float*)d_in[2];
    const float* Ap  = (const float*)d_in[3];
    const float* Ar  = (const float*)d_in[4];
    const float* V   = (const float*)d_in[5];
    const float* J   = (const float*)d_in[6];
    const float* R   = (const float*)d_in[7];
    const float* dHaV = (const float*)d_in[8];
    const float* dHaJ = (const float*)d_in[9];
    const float* dHaT = (const float*)d_in[10];
    const float* ToV  = (const float*)d_in[11];
    const float* ToJ  = (const float*)d_in[12];
    const float* ToT  = (const float*)d_in[13];
    const float* gmv  = (const float*)d_in[14];
    const void* mNL = d_in[15];
    const void* mFp = d_in[16];
    const void* mFj = d_in[17];

    detect_kernel<<<1, 64, 0, stream>>>(mNL, d_ws);
    fused_kernel<<<GRID, 256, 0, stream>>>(An, Ac, Aj, Ap, Ar, V, J, R,
                                           mNL, mFp, mFj, d_ws);
    final_kernel<<<1, 1024, 0, stream>>>(dHaV, dHaJ, dHaT, ToV, ToJ, ToT, gmv, d_ws,
                                         (float*)d_out);
}

// Round 3
// 86.099 us; speedup vs baseline: 1.1576x; 1.0204x over previous
//
#include <hip/hip_runtime.h>

#define C_ROWS 32768
#define L_COLS 512
#define N_TOT  (C_ROWS * (size_t)L_COLS)

#define NB_ROW 2048                // row-logic blocks (4 waves = 4 rows/iter, 4 iters)
#define NB_S   1536                // streaming blocks (An,Ar SSE + Ap apneg)
#define NB_MIX (NB_ROW + NB_S)     // 3584, interleaved 4:3 (groups of 7)
#define NB_ST  32                  // stats blocks
#define GRID   (NB_MIX + NB_ST)

// ws layout (bytes):
//   [0, 80)    : 10 doubles — masked-stats accumulators (zeroed by detect kernel)
//   [80, 84)   : int flag — mask storage: 0=bool byte, 1=int32, 2=float32
//   [128, ...) : NB_MIX * 2 doubles — per-block partials (misc|apneg, sse)

__device__ __forceinline__ float frelu(float x) { return x > 0.f ? x : 0.f; }

__device__ __forceinline__ float f4c(const float4& v, int k) {
    switch (k) { case 0: return v.x; case 1: return v.y; case 2: return v.z; default: return v.w; }
}

__device__ __forceinline__ bool mask_at(const void* p, int i, int flag) {
    if (flag == 1) return ((const int*)p)[i] != 0;
    if (flag == 2) return ((const float*)p)[i] != 0.f;
    return ((const unsigned char*)p)[i] != 0;
}

// ---------------------------------------------------------------- detect ----
__global__ void detect_kernel(const void* mask_nl, void* ws) {
    const int tid = threadIdx.x;                 // 64 threads
    const unsigned char* mb = (const unsigned char*)mask_nl;
    int mid_nz = 0, has3f = 0;
    for (int i = tid * 512; i < tid * 512 + 512; ++i) {
        unsigned char b = mb[i];
        if ((i & 3) && b) mid_nz = 1;
        if (b == 0x3f) has3f = 1;
    }
    unsigned long long bm = __ballot(mid_nz);
    unsigned long long bf = __ballot(has3f);
    if (tid < 10) ((double*)ws)[tid] = 0.0;
    if (tid == 0) {
        int flag = (bm == 0ull) ? 1 : (bf ? 2 : 0);
        *((int*)((char*)ws + 80)) = flag;
    }
}

// ----------------------------------------------------------------- fused ----
__global__ __launch_bounds__(256) void fused_kernel(const float* __restrict__ An,
                                                    const float* __restrict__ Ac,
                                                    const float* __restrict__ Aj,
                                                    const float* __restrict__ Ap,
                                                    const float* __restrict__ Ar,
                                                    const float* __restrict__ V,
                                                    const float* __restrict__ J,
                                                    const float* __restrict__ R,
                                                    const void* __restrict__ mNL,
                                                    const void* __restrict__ mFp,
                                                    const void* __restrict__ mFj,
                                                    void* ws) {
    double* part = (double*)((char*)ws + 128);
    const int bid = blockIdx.x;
    __shared__ double sA[4], sB[4];

    if (bid < NB_MIX) {
        const int g = bid / 7, o = bid - g * 7;
        const int lane = threadIdx.x & 63;
        const int wv   = threadIdx.x >> 6;

        if (o < 4) {
            // -------- row logic: Ac/Aj scan, one wave per row ----------------
            const int flag = *((const int*)((const char*)ws + 80));
            const int wid = (g * 4 + o) * 4 + wv;           // 0..8191
            double miscAcc = 0.0;
            for (int r = wid; r < C_ROWS; r += NB_ROW * 4) {
                const size_t base = (size_t)r * L_COLS;
                const int c0 = lane * 4;
                const float4 ac0 = *(const float4*)(Ac + base + c0);
                const float4 aj0 = *(const float4*)(Aj + base + c0);
                const float4 ac1 = *(const float4*)(Ac + base + 256 + c0);
                const float4 aj1 = *(const float4*)(Aj + base + 256 + c0);
                float lsAj = 0.f, lsAc = 0.f;
                unsigned long long key = ~0ull;
#pragma unroll
                for (int k = 0; k < 4; ++k) {
                    const float dd = f4c(ac0, k) - f4c(aj0, k);
                    lsAj += frelu(-dd); lsAc += frelu(dd);
                    const unsigned long long kk =
                        ((unsigned long long)__float_as_uint(fabsf(dd)) << 32) |
                        (unsigned)(c0 + k);
                    key = kk < key ? kk : key;
                }
#pragma unroll
                for (int k = 0; k < 4; ++k) {
                    const int col = 256 + c0 + k;
                    const float dd = f4c(ac1, k) - f4c(aj1, k);
                    if (col < L_COLS - 1) {
                        lsAj += frelu(-dd); lsAc += frelu(dd);
                        const unsigned long long kk =
                            ((unsigned long long)__float_as_uint(fabsf(dd)) << 32) |
                            (unsigned)col;
                        key = kk < key ? kk : key;
                    }
                }
#pragma unroll
                for (int off = 32; off; off >>= 1) {
                    const unsigned long long ok = __shfl_xor(key, off);
                    key = ok < key ? ok : key;
                    lsAj += __shfl_xor(lsAj, off);
                    lsAc += __shfl_xor(lsAc, off);
                }
                const float eAc = __shfl(ac1.w, 63);
                const float eAj = __shfl(aj1.w, 63);
                if (lane == 0) {
                    const int idx = (int)(key & 0xffffffffull);
                    const float bAj = Aj[base + idx];
                    const float bAp = Ap[base + idx];
                    const float eAp = Ap[base + L_COLS - 1];
                    const float mAp = mask_at(mFp, r, flag) ? 1.f : 0.f;
                    const float mAj = mask_at(mFj, r, flag) ? 1.f : 0.f;
                    miscAcc += 0.15 * (double)(mAp * frelu(eAp - eAj))
                             + (double)(mAj * frelu(eAj - eAc))
                             + 5.0 * (double)frelu(1.1f * bAj - bAp)
                             + (double)(mAj * (frelu(8.f - lsAj) + frelu(8.f - lsAc)));
                }
            }
            if (lane == 0) { sA[wv] = miscAcc; sB[wv] = 0.0; }
        } else {
            // -------- streaming: SSE(An-Ar) + sum(relu(-Ap)) -----------------
            const int sBlk = g * 3 + (o - 4);               // 0..1535
            const size_t i0 = (size_t)sBlk * 256 + threadIdx.x;
            const size_t stride = (size_t)NB_S * 256;
            const size_t N4 = N_TOT / 4;
            const float4* a4 = (const float4*)An;
            const float4* r4 = (const float4*)Ar;
            const float4* p4 = (const float4*)Ap;
            double sse = 0.0, apn = 0.0;
            for (size_t i = i0; i < N4; i += stride) {
                const float4 a = a4[i], r = r4[i], p = p4[i];
                const float dx = a.x - r.x, dy = a.y - r.y,
                            dz = a.z - r.z, dw = a.w - r.w;
                sse += (double)(dx * dx + dy * dy) + (double)(dz * dz + dw * dw);
                apn += (double)(frelu(-p.x) + frelu(-p.y) + frelu(-p.z) + frelu(-p.w));
            }
#pragma unroll
            for (int off = 32; off; off >>= 1) {
                sse += __shfl_xor(sse, off);
                apn += __shfl_xor(apn, off);
            }
            if (lane == 0) { sA[wv] = apn; sB[wv] = sse; }
        }
        __syncthreads();
        if (threadIdx.x == 0) {
            part[2 * bid]     = sA[0] + sA[1] + sA[2] + sA[3];
            part[2 * bid + 1] = sB[0] + sB[1] + sB[2] + sB[3];
        }
    } else {
        // -------- masked stats over C-length arrays --------------------------
        const int flag = *((const int*)((const char*)ws + 80));
        double a[10];
#pragma unroll
        for (int k = 0; k < 10; ++k) a[k] = 0.0;
        for (int i = (bid - NB_MIX) * 256 + threadIdx.x; i < C_ROWS; i += NB_ST * 256) {
            const float v = V[i], j = J[i], r = R[i];
            if (mask_at(mNL, i, flag)) {
                a[0] += 1.0;
                a[1] += (double)v; a[2] += (double)v * v;
                a[3] += (double)j; a[4] += (double)j * j; a[5] += (double)j * v;
                a[6] += (double)r; a[7] += (double)r * r; a[8] += (double)r * v;
            }
            a[9] += (double)frelu(-r);
        }
#pragma unroll
        for (int k = 0; k < 10; ++k)
            for (int off = 32; off; off >>= 1) a[k] += __shfl_xor(a[k], off);
        if ((threadIdx.x & 63) == 0) {
#pragma unroll
            for (int k = 0; k < 10; ++k) atomicAdd(&((double*)ws)[k], a[k]);
        }
    }
}

// ----------------------------------------------------------------- final ----
__device__ double corrterm(double n, double Sx, double Sxx, double Sy, double Syy,
                           double Sxy, double target) {
    const double mx = Sx / n, my = Sy / n;
    const double cov = Sxy - n * mx * my;
    const double vx  = Sxx - n * mx * mx;
    const double vy  = Syy - n * my * my;
    double cost = cov / (sqrt(vx) * sqrt(vy));
    if (isnan(cost)) cost = 0.0;
    const double cmin = cost < target ? cost : target;
    return target - cmin;
}

__global__ __launch_bounds__(1024) void final_kernel(const float* __restrict__ dHaV,
                                                     const float* __restrict__ dHaJ,
                                                     const float* __restrict__ dHaT,
                                                     const float* __restrict__ ToV,
                                                     const float* __restrict__ ToJ,
                                                     const float* __restrict__ ToT,
                                                     const float* __restrict__ gm,
                                                     void* ws, float* out) {
    __shared__ double sm[1024], ss[1024];
    double m = 0.0, s = 0.0;
    const double* part = (const double*)((const char*)ws + 128);
    for (int i = threadIdx.x; i < NB_MIX; i += 1024) { m += part[2 * i]; s += part[2 * i + 1]; }
    sm[threadIdx.x] = m; ss[threadIdx.x] = s;
    __syncthreads();
    for (int off = 512; off; off >>= 1) {
        if (threadIdx.x < (unsigned)off) {
            sm[threadIdx.x] += sm[threadIdx.x + off];
            ss[threadIdx.x] += ss[threadIdx.x + off];
        }
        __syncthreads();
    }
    if (threadIdx.x == 0) {
        double total = sm[0] + 10.0 * ss[0] / (double)N_TOT;
        const double* st = (const double*)ws;
        total += corrterm(st[0], st[3], st[4], st[1], st[2], st[5], 0.7);
        total += corrterm(st[0], st[6], st[7], st[1], st[2], st[8], 0.4);
        total += st[9];                     // sum(relu(-Rd25))
        double p = 0.0;
        for (int i = 0; i < 8; ++i) {
            p += 10.0 * (double)frelu(-dHaV[i]) + (double)frelu(-dHaJ[i]) + (double)frelu(-dHaT[i]);
            p += (double)frelu(273.15f - ToV[i]) + (double)frelu(273.15f - ToJ[i])
               + (double)frelu(273.15f - ToT[i]);
            p += (double)frelu(-gm[i]);
        }
        total += p;
        out[0] = (float)total;
    }
}

extern "C" void kernel_launch(void* const* d_in, const int* in_sizes, int n_in,
                              void* d_out, int out_size, void* d_ws, size_t ws_size,
                              hipStream_t stream) {
    const float* An  = (const float*)d_in[0];
    const float* Ac  = (const float*)d_in[1];
    const float* Aj  = (const float*)d_in[2];
    const float* Ap  = (const float*)d_in[3];
    const float* Ar  = (const float*)d_in[4];
    const float* V   = (const float*)d_in[5];
    const float* J   = (const float*)d_in[6];
    const float* R   = (const float*)d_in[7];
    const float* dHaV = (const float*)d_in[8];
    const float* dHaJ = (const float*)d_in[9];
    const float* dHaT = (const float*)d_in[10];
    const float* ToV  = (const float*)d_in[11];
    const float* ToJ  = (const float*)d_in[12];
    const float* ToT  = (const float*)d_in[13];
    const float* gmv  = (const float*)d_in[14];
    const void* mNL = d_in[15];
    const void* mFp = d_in[16];
    const void* mFj = d_in[17];

    detect_kernel<<<1, 64, 0, stream>>>(mNL, d_ws);
    fused_kernel<<<GRID, 256, 0, stream>>>(An, Ac, Aj, Ap, Ar, V, J, R,
                                           mNL, mFp, mFj, d_ws);
    final_kernel<<<1, 1024, 0, stream>>>(dHaV, dHaJ, dHaT, ToV, ToJ, ToT, gmv, d_ws,
                                         (float*)d_out);
}